// Round 1
// baseline (100.703 us; speedup 1.0000x reference)
//
#include <hip/hip_runtime.h>
#include <math.h>

#define RES_W 256
#define RES_H 256
#define TF_RES 128
#define GROUP 4

typedef float float2u __attribute__((ext_vector_type(2), aligned(4)));

// One thread per ray, GROUP-sample software-pipelined march with per-lane
// exec-mask termination.
// Theory (R1): at 1 wave/SIMD (1024 waves total) the old one-sample-at-a-time
// loop serialized {4 gathers -> trilerp -> TF -> Texcl -> ballot} per sample:
// latency-bound, ~3-6x above the TA-throughput floor (~6.5us at 2.1 cyc/lane-addr).
// Fix: sample positions depend only on k, so issue all GROUP*4 gathers up front
// (masked by !done), then process the GROUP samples back-to-back with bit-exact
// per-sample op order. Serial latency exposures/ray: ~7.2 -> ~2.2.
__global__ __launch_bounds__(64, 1) void raycast_kernel(
    const float* __restrict__ vol,    // [256,256,256] x-major: idx = (x<<16)+(y<<8)+z
    const float* __restrict__ tf,     // [128,4]
    const float* __restrict__ cam_p,  // [3]
    const int*   __restrict__ sr_p,   // [1]
    float* __restrict__ out)          // [256,256,5]  idx = (w*256+h)*5+c
{
    #pragma clang fp contract(off)

    // 129-entry SoA TF tables: [128] dups [127] so (lo,lo+1) is always an
    // adjacent-dword pair -> ds_read2_b32; exact at the lo==127 edge.
    __shared__ float tfR[TF_RES + 1], tfG[TF_RES + 1], tfB[TF_RES + 1], tfA[TF_RES + 1];
    const int tid = (int)threadIdx.x;          // 0..63
    {
        const float4* tf4 = (const float4*)tf;
        float4 e0 = tf4[tid];
        float4 e1 = tf4[tid + 64];
        tfR[tid] = e0.x; tfG[tid] = e0.y; tfB[tid] = e0.z; tfA[tid] = e0.w;
        tfR[tid + 64] = e1.x; tfG[tid + 64] = e1.y; tfB[tid + 64] = e1.z; tfA[tid + 64] = e1.w;
        if (tid == 63) {
            tfR[TF_RES] = e1.x; tfG[TF_RES] = e1.y; tfB[TF_RES] = e1.z; tfA[TF_RES] = e1.w;
        }
    }
    __syncthreads();

    // 1024 blocks x 64 threads; wave = 8x8 pixel tile (coherent gather front).
    // XCD swizzle: block b -> XCD b%8 gets a contiguous image slab for L2 locality.
    const int b    = (int)blockIdx.x;          // 0..1023
    const int tile = (b % 8) * 128 + (b / 8);  // 0..1023
    const int tile_h = tile % 32;
    const int tile_w = tile / 32;
    const int h = tile_h * 8 + (tid % 8);      // H index (v axis)
    const int w = tile_w * 8 + (tid / 8);      // W index (u axis)

    const float cx = cam_p[0], cy = cam_p[1], cz = cam_p[2];
    const int   sr_i = sr_p[0];
    const float srf = (float)sr_i;

    // ---- camera basis, fp32, numpy op order, no FMA (bit-matches reference) ----
    float nx = -cx, ny = -cy, nz = -cz;
    float fl = __fsqrt_rn((nx*nx + ny*ny) + nz*nz);
    float fx = nx / fl, fy = ny / fl, fz = nz / fl;
    float rxu = 0.0f - fz;
    float rzu = fx;
    float rl = __fsqrt_rn((rxu*rxu + 0.0f) + rzu*rzu);
    float rx = rxu / rl, rz = rzu / rl;
    float ux = 0.0f - rz*fy;
    float uy = rz*fx - rx*fz;
    float uz = rx*fy;

    const float ang32 = (float)((30.0 * 0.017453292519943295) * 0.5);
    const float tan_half = (float)tan((double)ang32);

    float uu = ((((float)w + 0.5f) / 256.0f) * 2.0f - 1.0f) * tan_half;
    float vv = ((((float)h + 0.5f) / 256.0f) * 2.0f - 1.0f) * tan_half;

    float dx = (fx + uu*rx) + vv*ux;
    float dy = (fy + 0.0f ) + vv*uy;
    float dz = (fz + uu*rz) + vv*uz;
    float dl = __fsqrt_rn((dx*dx + dy*dy) + dz*dz);
    dx = dx / dl; dy = dy / dl; dz = dz / dl;

    float ivx = 1.0f/dx, ivy = 1.0f/dy, ivz = 1.0f/dz;
    float tlx = (-1.0f - cx)*ivx, thx = (1.0f - cx)*ivx;
    float tly = (-1.0f - cy)*ivy, thy = (1.0f - cy)*ivy;
    float tlz = (-1.0f - cz)*ivz, thz = (1.0f - cz)*ivz;
    float tmin = fmaxf(fmaxf(fminf(tlx,thx), fminf(tly,thy)), fminf(tlz,thz));
    float tmax = fminf(fminf(fmaxf(tlx,thx), fmaxf(tly,thy)), fmaxf(tlz,thz));
    bool hit = (tmax >= 0.0f) && (tmin <= tmax);

    float entry = fmaxf(tmin, 0.1f);
    float dist  = hit ? fmaxf(tmax - entry, 0.0f) : 0.0f;
    float nsf   = fminf(fmaxf(ceilf(((dist * 0.5f) * 256.0f) * srf), 1.0f), 384.0f);
    int   ns    = (int)nsf;
    float step  = dist / nsf;

    float rgb_r = 0.0f, rgb_g = 0.0f, rgb_b = 0.0f, acc = 0.0f;
    float Texcl = 1.0f;
    float depth = 1.0f;
    bool  found = false;
    bool  done  = !hit;
    int   k = 0;

    for (;;) {
        // ---- phase 1: issue all GROUP samples' gathers (masked by !done) ----
        // Staged per-sample state lives in registers (fully unrolled, static idx).
        float2u q00[GROUP], q10[GROUP], q01[GROUP], q11[GROUP];
        float   gt[GROUP], gfx[GROUP], gfy[GROUP], gfz[GROUP];
        bool    z255[GROUP];
        if (!done) {
            #pragma unroll
            for (int j = 0; j < GROUP; ++j) {
                // sample index = k + j (k only advances in phase 2) -> same value
                // the old loop used; bit-exact op order below.
                float t  = entry + ((float)(k + j) + 0.5f) * step;
                float px = (cx + t*dx);
                float py = (cy + t*dy);
                float pz = (cz + t*dz);
                px = ((px * 0.5f) + 0.5f) * 255.0f;
                py = ((py * 0.5f) + 0.5f) * 255.0f;
                pz = ((pz * 0.5f) + 0.5f) * 255.0f;
                px = fminf(fmaxf(px, 0.0f), 255.0f);
                py = fminf(fmaxf(py, 0.0f), 255.0f);
                pz = fminf(fmaxf(pz, 0.0f), 255.0f);
                int x0 = (int)px, y0 = (int)py, z0 = (int)pz;   // >=0: trunc == floor
                gfx[j] = px - (float)x0;
                gfy[j] = py - (float)y0;
                gfz[j] = pz - (float)z0;
                int x1 = min(x0 + 1, 255);
                int y1 = min(y0 + 1, 255);
                int zb = min(z0, 254);            // z-pair base; z0==255 -> ffz==0 exactly
                int bx0 = x0 << 16, bx1 = x1 << 16;
                int by0 = y0 << 8,  by1 = y1 << 8;
                q00[j] = *(const float2u*)(vol + (bx0 + by0 + zb));
                q10[j] = *(const float2u*)(vol + (bx1 + by0 + zb));
                q01[j] = *(const float2u*)(vol + (bx0 + by1 + zb));
                q11[j] = *(const float2u*)(vol + (bx1 + by1 + zb));
                z255[j] = (z0 == 255);
                gt[j] = t;
            }
        }

        // ---- phase 2: process the GROUP samples back-to-back (bit-exact) ----
        #pragma unroll
        for (int j = 0; j < GROUP; ++j) {
            if (!done) {
                float2u p00 = q00[j], p10 = q10[j], p01 = q01[j], p11 = q11[j];
                if (z255[j]) {                // tap z0 must read index 255 = pair.y
                    p00.x = p00.y; p10.x = p10.y; p01.x = p01.y; p11.x = p11.y;
                }
                float ffx = gfx[j], ffy = gfy[j], ffz = gfz[j];
                float omx = 1.0f - ffx, omy = 1.0f - ffy, omz = 1.0f - ffz;
                float c00 = p00.x*omx + p10.x*ffx;
                float c10 = p01.x*omx + p11.x*ffx;
                float c01 = p00.y*omx + p10.y*ffx;
                float c11 = p01.y*omx + p11.y*ffx;
                float c0  = c00*omy + c10*ffy;
                float c1  = c01*omy + c11*ffy;
                float intensity = c0*omz + c1*ffz;

                // ---- TF lookup (adjacent-pair LDS reads) ----
                float xi = fminf(fmaxf(intensity, 0.0f), 1.0f) * 127.0f;
                int lo  = (int)xi;
                float tfr = xi - (float)lo;
                float omt = 1.0f - tfr;
                float cr  = tfR[lo]*omt + tfR[lo + 1]*tfr;
                float cg  = tfG[lo]*omt + tfG[lo + 1]*tfr;
                float cbb = tfB[lo]*omt + tfB[lo + 1]*tfr;
                float a   = tfA[lo]*omt + tfA[lo + 1]*tfr;

                if (sr_i == 1) {
                    a = 1.0f - (1.0f - a);            // double rounding, as numpy
                } else {
                    a = 1.0f - powf(1.0f - a, 1.0f / srf);
                }
                float one_m = 1.0f - a;
                float wgt = Texcl * a;
                rgb_r += wgt * cr;
                rgb_g += wgt * cg;
                rgb_b += wgt * cbb;
                acc   += wgt;
                if (!found && a > 1e-3f) {
                    found = true;
                    depth = (gt[j] - 0.1f) / 99.9f;
                }
                Texcl = Texcl * one_m;
                k++;
                // T<2e-3 guarantees some a>0.016>1e-3 occurred, so depth is set;
                // dropped tail contributes <= Texcl < 2e-3 per channel (budget ok).
                done = (k >= ns) || (Texcl < 2e-3f);
            }
        }
        if (__ballot(!done) == 0ULL) break;
    }

    {
        int oi = (w * RES_H + h) * 5;
        out[oi + 0] = rgb_r;
        out[oi + 1] = rgb_g;
        out[oi + 2] = rgb_b;
        out[oi + 3] = acc;
        out[oi + 4] = depth;
    }
}

extern "C" void kernel_launch(void* const* d_in, const int* in_sizes, int n_in,
                              void* d_out, int out_size, void* d_ws, size_t ws_size,
                              hipStream_t stream) {
    const float* vol = (const float*)d_in[0];
    const float* tf  = (const float*)d_in[1];
    const float* cam = (const float*)d_in[2];
    const int*   sr  = (const int*)d_in[3];
    float* out = (float*)d_out;

    raycast_kernel<<<dim3(1024), dim3(64), 0, stream>>>(vol, tf, cam, sr, out);
}

// Round 2
// 100.396 us; speedup vs baseline: 1.0031x; 1.0031x over previous
//
#include <hip/hip_runtime.h>
#include <math.h>

#define RES_W 256
#define RES_H 256
#define TF_RES 128

typedef float float2u __attribute__((ext_vector_type(2), aligned(4)));

// One thread per ray, serial march with per-lane exec-mask termination.
// TA-throughput model (validated R1): kernel cyc/CU ~= 2.1 * active
// lane-addresses/CU -> ~6.5us floor at 7.2 samples * 4 z-pair taps per ray.
// R1 A/B: GROUP=4 lookahead (+~20% speculative addresses) cost +1.1us,
// matching the model's +1.3us prediction; latency gain ~0 (4 waves/CU already
// overlap). Serial+mask issues ONLY needed addresses -> measured optimum.
// dur_us residual beyond this kernel is harness poison fills (2x256MiB at
// ~41us each, 80% HBM roofline) + launch gaps.
__global__ __launch_bounds__(64) void raycast_kernel(
    const float* __restrict__ vol,    // [256,256,256] x-major: idx = (x<<16)+(y<<8)+z
    const float* __restrict__ tf,     // [128,4]
    const float* __restrict__ cam_p,  // [3]
    const int*   __restrict__ sr_p,   // [1]
    float* __restrict__ out)          // [256,256,5]  idx = (w*256+h)*5+c
{
    #pragma clang fp contract(off)

    // 129-entry SoA TF tables: [128] dups [127] so (lo,lo+1) is always an
    // adjacent-dword pair -> ds_read2_b32; exact at the lo==127 edge.
    __shared__ float tfR[TF_RES + 1], tfG[TF_RES + 1], tfB[TF_RES + 1], tfA[TF_RES + 1];
    const int tid = (int)threadIdx.x;          // 0..63
    {
        const float4* tf4 = (const float4*)tf;
        float4 e0 = tf4[tid];
        float4 e1 = tf4[tid + 64];
        tfR[tid] = e0.x; tfG[tid] = e0.y; tfB[tid] = e0.z; tfA[tid] = e0.w;
        tfR[tid + 64] = e1.x; tfG[tid + 64] = e1.y; tfB[tid + 64] = e1.z; tfA[tid + 64] = e1.w;
        if (tid == 63) {
            tfR[TF_RES] = e1.x; tfG[TF_RES] = e1.y; tfB[TF_RES] = e1.z; tfA[TF_RES] = e1.w;
        }
    }
    __syncthreads();

    // 1024 blocks x 64 threads; wave = 8x8 pixel tile (coherent gather front).
    // XCD swizzle: block b -> XCD b%8 gets a contiguous image slab for L2 locality.
    const int b    = (int)blockIdx.x;          // 0..1023
    const int tile = (b % 8) * 128 + (b / 8);  // 0..1023
    const int tile_h = tile % 32;
    const int tile_w = tile / 32;
    const int h = tile_h * 8 + (tid % 8);      // H index (v axis)
    const int w = tile_w * 8 + (tid / 8);      // W index (u axis)

    const float cx = cam_p[0], cy = cam_p[1], cz = cam_p[2];
    const int   sr_i = sr_p[0];
    const float srf = (float)sr_i;

    // ---- camera basis, fp32, numpy op order, no FMA (bit-matches reference) ----
    float nx = -cx, ny = -cy, nz = -cz;
    float fl = __fsqrt_rn((nx*nx + ny*ny) + nz*nz);
    float fx = nx / fl, fy = ny / fl, fz = nz / fl;
    float rxu = 0.0f - fz;
    float rzu = fx;
    float rl = __fsqrt_rn((rxu*rxu + 0.0f) + rzu*rzu);
    float rx = rxu / rl, rz = rzu / rl;
    float ux = 0.0f - rz*fy;
    float uy = rz*fx - rx*fz;
    float uz = rx*fy;

    const float ang32 = (float)((30.0 * 0.017453292519943295) * 0.5);
    const float tan_half = (float)tan((double)ang32);

    float uu = ((((float)w + 0.5f) / 256.0f) * 2.0f - 1.0f) * tan_half;
    float vv = ((((float)h + 0.5f) / 256.0f) * 2.0f - 1.0f) * tan_half;

    float dx = (fx + uu*rx) + vv*ux;
    float dy = (fy + 0.0f ) + vv*uy;
    float dz = (fz + uu*rz) + vv*uz;
    float dl = __fsqrt_rn((dx*dx + dy*dy) + dz*dz);
    dx = dx / dl; dy = dy / dl; dz = dz / dl;

    float ivx = 1.0f/dx, ivy = 1.0f/dy, ivz = 1.0f/dz;
    float tlx = (-1.0f - cx)*ivx, thx = (1.0f - cx)*ivx;
    float tly = (-1.0f - cy)*ivy, thy = (1.0f - cy)*ivy;
    float tlz = (-1.0f - cz)*ivz, thz = (1.0f - cz)*ivz;
    float tmin = fmaxf(fmaxf(fminf(tlx,thx), fminf(tly,thy)), fminf(tlz,thz));
    float tmax = fminf(fminf(fmaxf(tlx,thx), fmaxf(tly,thy)), fmaxf(tlz,thz));
    bool hit = (tmax >= 0.0f) && (tmin <= tmax);

    float entry = fmaxf(tmin, 0.1f);
    float dist  = hit ? fmaxf(tmax - entry, 0.0f) : 0.0f;
    float nsf   = fminf(fmaxf(ceilf(((dist * 0.5f) * 256.0f) * srf), 1.0f), 384.0f);
    int   ns    = (int)nsf;
    float step  = dist / nsf;

    float rgb_r = 0.0f, rgb_g = 0.0f, rgb_b = 0.0f, acc = 0.0f;
    float Texcl = 1.0f;
    float depth = 1.0f;
    bool  found = false;
    bool  done  = !hit;
    int   k = 0;

    for (;;) {
        if (!done) {
            // ---- sample k (bit-exact reference op order) ----
            float t  = entry + ((float)k + 0.5f) * step;
            float px = (cx + t*dx);
            float py = (cy + t*dy);
            float pz = (cz + t*dz);
            px = ((px * 0.5f) + 0.5f) * 255.0f;
            py = ((py * 0.5f) + 0.5f) * 255.0f;
            pz = ((pz * 0.5f) + 0.5f) * 255.0f;
            px = fminf(fmaxf(px, 0.0f), 255.0f);
            py = fminf(fmaxf(py, 0.0f), 255.0f);
            pz = fminf(fmaxf(pz, 0.0f), 255.0f);
            int x0 = (int)px, y0 = (int)py, z0 = (int)pz;   // >=0: trunc == floor
            float ffx = px - (float)x0;
            float ffy = py - (float)y0;
            float ffz = pz - (float)z0;
            int x1 = min(x0 + 1, 255);
            int y1 = min(y0 + 1, 255);
            int zb = min(z0, 254);            // z-pair base; z0==255 -> ffz==0 exactly
            int bx0 = x0 << 16, bx1 = x1 << 16;
            int by0 = y0 << 8,  by1 = y1 << 8;
            float2u p00 = *(const float2u*)(vol + (bx0 + by0 + zb));
            float2u p10 = *(const float2u*)(vol + (bx1 + by0 + zb));
            float2u p01 = *(const float2u*)(vol + (bx0 + by1 + zb));
            float2u p11 = *(const float2u*)(vol + (bx1 + by1 + zb));
            if (z0 == 255) {                  // tap z0 must read index 255 = pair.y
                p00.x = p00.y; p10.x = p10.y; p01.x = p01.y; p11.x = p11.y;
            }

            float omx = 1.0f - ffx, omy = 1.0f - ffy, omz = 1.0f - ffz;
            float c00 = p00.x*omx + p10.x*ffx;
            float c10 = p01.x*omx + p11.x*ffx;
            float c01 = p00.y*omx + p10.y*ffx;
            float c11 = p01.y*omx + p11.y*ffx;
            float c0  = c00*omy + c10*ffy;
            float c1  = c01*omy + c11*ffy;
            float intensity = c0*omz + c1*ffz;

            // ---- TF lookup (adjacent-pair LDS reads) ----
            float xi = fminf(fmaxf(intensity, 0.0f), 1.0f) * 127.0f;
            int lo  = (int)xi;
            float tfr = xi - (float)lo;
            float omt = 1.0f - tfr;
            float cr  = tfR[lo]*omt + tfR[lo + 1]*tfr;
            float cg  = tfG[lo]*omt + tfG[lo + 1]*tfr;
            float cbb = tfB[lo]*omt + tfB[lo + 1]*tfr;
            float a   = tfA[lo]*omt + tfA[lo + 1]*tfr;

            if (sr_i == 1) {
                a = 1.0f - (1.0f - a);            // double rounding, as numpy
            } else {
                a = 1.0f - powf(1.0f - a, 1.0f / srf);
            }
            float one_m = 1.0f - a;
            float wgt = Texcl * a;
            rgb_r += wgt * cr;
            rgb_g += wgt * cg;
            rgb_b += wgt * cbb;
            acc   += wgt;
            if (!found && a > 1e-3f) {
                found = true;
                depth = (t - 0.1f) / 99.9f;
            }
            Texcl = Texcl * one_m;
            k++;
            // T<2e-3 guarantees some a>0.016>1e-3 occurred, so depth is set;
            // dropped tail contributes <= Texcl < 2e-3 per channel (budget ok).
            done = (k >= ns) || (Texcl < 2e-3f);
        }
        if (__ballot(!done) == 0ULL) break;
    }

    {
        int oi = (w * RES_H + h) * 5;
        out[oi + 0] = rgb_r;
        out[oi + 1] = rgb_g;
        out[oi + 2] = rgb_b;
        out[oi + 3] = acc;
        out[oi + 4] = depth;
    }
}

extern "C" void kernel_launch(void* const* d_in, const int* in_sizes, int n_in,
                              void* d_out, int out_size, void* d_ws, size_t ws_size,
                              hipStream_t stream) {
    const float* vol = (const float*)d_in[0];
    const float* tf  = (const float*)d_in[1];
    const float* cam = (const float*)d_in[2];
    const int*   sr  = (const int*)d_in[3];
    float* out = (float*)d_out;

    raycast_kernel<<<dim3(1024), dim3(64), 0, stream>>>(vol, tf, cam, sr, out);
}